// Round 2
// baseline (128.829 us; speedup 1.0000x reference)
//
#include <hip/hip_runtime.h>
#include <hip/hip_bf16.h>

#define B_ 4
#define S_ 4096
#define DM 1024
#define H_ 16
#define HD 64
#define BH (B_*H_)
#define SPLIT 16
#define CHUNK (S_/SPLIT)   // 256

typedef __attribute__((ext_vector_type(8))) __bf16 bf16x8;
typedef __attribute__((ext_vector_type(4))) __bf16 bf16x4;
typedef __attribute__((ext_vector_type(4))) float f32x4;

#define MFMA16(a,b,c) __builtin_amdgcn_mfma_f32_16x16x32_bf16((a),(b),(c),0,0,0)

__device__ __forceinline__ void gload_lds16(const void* g, void* l) {
  __builtin_amdgcn_global_load_lds(
      (const __attribute__((address_space(1))) void*)g,
      (__attribute__((address_space(3))) void*)l, 16, 0, 0);
}

// ---------------------------------------------------------------------------
// K0: convert W (f32 [1024][1024]) to bf16 ws buffer, same [n][k] layout.
// ---------------------------------------------------------------------------
__global__ __launch_bounds__(256)
void k0_convw(const float* __restrict__ Wg, __bf16* __restrict__ Wb) {
  const size_t i = (size_t)blockIdx.x * 256 + threadIdx.x;   // 1024 blocks
  f32x4 w = *reinterpret_cast<const f32x4*>(Wg + i * 4);
  bf16x4 o;
#pragma unroll
  for (int j = 0; j < 4; ++j) o[j] = (__bf16)w[j];
  *reinterpret_cast<bf16x4*>(Wb + i * 4) = o;
}

// ---------------------------------------------------------------------------
// K1: partial KV[split][bh][d][e] = sum_{s in chunk} K[s][d] * V[s][e]  (f32)
// grid = SPLIT*BH = 1024 blocks, 256 threads (4 waves).
// f32 global loads (float4, coalesced), convert to bf16, store TRANSPOSED
// into padded LDS (Kt[d][s], Vt[e][s], LDP=264 -> row stride 528B).
// ---------------------------------------------------------------------------
__global__ __launch_bounds__(256)
void k1_kv_partial(const float* __restrict__ Kg,
                   const float* __restrict__ Vg,
                   float* __restrict__ partial) {
  constexpr int LDP = 264;
  __shared__ __align__(16) __bf16 Kt[64 * LDP];
  __shared__ __align__(16) __bf16 Vt[64 * LDP];
  const int bid = blockIdx.x;
  const int split = bid >> 6;
  const int bh = bid & (BH - 1);
  const int b = bh >> 4, h = bh & 15;
  const int s0 = split * CHUNK;
  const int t = threadIdx.x;
  const float* Kbase = Kg + ((size_t)b * S_ + s0) * DM + h * HD;
  const float* Vbase = Vg + ((size_t)b * S_ + s0) * DM + h * HD;
  const int c = t & 15, sr = t >> 4;   // 16 d-chunks x 16 s-rows per iter
  const int d0 = c * 4;
#pragma unroll
  for (int it = 0; it < 16; ++it) {
    const int s = it * 16 + sr;
    f32x4 kv = *reinterpret_cast<const f32x4*>(Kbase + (size_t)s * DM + d0);
    f32x4 vv = *reinterpret_cast<const f32x4*>(Vbase + (size_t)s * DM + d0);
#pragma unroll
    for (int j = 0; j < 4; ++j) {
      Kt[(d0 + j) * LDP + s] = (__bf16)kv[j];
      Vt[(d0 + j) * LDP + s] = (__bf16)vv[j];
    }
  }
  __syncthreads();
  const int w = t >> 6, l = t & 63, lr = l & 15, lg = l >> 4;
  f32x4 acc[4] = {};
#pragma unroll
  for (int ks = 0; ks < 8; ++ks) {
    bf16x8 a = *reinterpret_cast<const bf16x8*>(&Kt[(w * 16 + lr) * LDP + ks * 32 + lg * 8]);
#pragma unroll
    for (int n = 0; n < 4; ++n) {
      bf16x8 bb = *reinterpret_cast<const bf16x8*>(&Vt[(n * 16 + lr) * LDP + ks * 32 + lg * 8]);
      acc[n] = MFMA16(a, bb, acc[n]);
    }
  }
  float* dst = partial + ((size_t)(split * BH + bh) << 12);  // *64*64
#pragma unroll
  for (int n = 0; n < 4; ++n)
#pragma unroll
    for (int r = 0; r < 4; ++r) {
      const int d = w * 16 + lg * 4 + r;
      const int e = n * 16 + lr;
      dst[d * 64 + e] = acc[n][r];
    }
}

// ---------------------------------------------------------------------------
// K2: reduce the 16 partials, emit KVt[bh][e][d] bf16 (transposed so K3's
// B-fragments are contiguous 16B loads).  grid = BH = 64 blocks.
// ---------------------------------------------------------------------------
__global__ __launch_bounds__(256)
void k2_kv_reduce(const float* __restrict__ partial,
                  __bf16* __restrict__ kvt) {
  __shared__ float lds[64 * 65];
  const int bh = blockIdx.x, t = threadIdx.x;
#pragma unroll
  for (int i = 0; i < 16; ++i) {
    const int idx = i * 256 + t;         // = d*64 + e
    float s = 0.f;
#pragma unroll
    for (int sp = 0; sp < SPLIT; ++sp)
      s += partial[((size_t)(sp * BH + bh) << 12) + idx];
    lds[(idx >> 6) * 65 + (idx & 63)] = s;
  }
  __syncthreads();
#pragma unroll
  for (int i = 0; i < 16; ++i) {
    const int idx = i * 256 + t;         // = e*64 + d
    const int e = idx >> 6, d = idx & 63;
    kvt[((size_t)bh << 12) + idx] = (__bf16)lds[d * 65 + e];
  }
}

// ---------------------------------------------------------------------------
// K3: z[b][s][h*64+e] = sum_d Q[b][s][h*64+d] * KV[b][h][d][e]
// grid = B*(S/64) = 256 blocks. Pure-register MFMA: A-frags direct from
// global f32 Q (converted), B-frags from L2-hot bf16 kvt. z written bf16.
// ---------------------------------------------------------------------------
__global__ __launch_bounds__(256)
void k3_z(const float* __restrict__ Qg,
          const __bf16* __restrict__ kvt,
          __bf16* __restrict__ z) {
  const int bid = blockIdx.x;
  const int b = bid >> 6, sc = bid & 63;
  const int s0 = sc * 64;
  const int t = threadIdx.x, w = t >> 6, l = t & 63, lr = l & 15, lg = l >> 4;
  const float* qrow = Qg + ((size_t)b * S_ + s0 + w * 16 + lr) * DM;
#pragma unroll 1
  for (int h = 0; h < H_; ++h) {
    const __bf16* kvh = kvt + ((size_t)(b * H_ + h) << 12);
    f32x4 q0 = *reinterpret_cast<const f32x4*>(qrow + h * 64 + lg * 8);
    f32x4 q1 = *reinterpret_cast<const f32x4*>(qrow + h * 64 + lg * 8 + 4);
    f32x4 q2 = *reinterpret_cast<const f32x4*>(qrow + h * 64 + 32 + lg * 8);
    f32x4 q3 = *reinterpret_cast<const f32x4*>(qrow + h * 64 + 32 + lg * 8 + 4);
    bf16x8 a0, a1;
#pragma unroll
    for (int j = 0; j < 4; ++j) {
      a0[j] = (__bf16)q0[j]; a0[4 + j] = (__bf16)q1[j];
      a1[j] = (__bf16)q2[j]; a1[4 + j] = (__bf16)q3[j];
    }
    f32x4 acc[4] = {};
#pragma unroll
    for (int n = 0; n < 4; ++n) {
      bf16x8 b0 = *reinterpret_cast<const bf16x8*>(kvh + (n * 16 + lr) * 64 + lg * 8);
      bf16x8 b1 = *reinterpret_cast<const bf16x8*>(kvh + (n * 16 + lr) * 64 + 32 + lg * 8);
      acc[n] = MFMA16(a0, b0, acc[n]);
      acc[n] = MFMA16(a1, b1, acc[n]);
    }
#pragma unroll
    for (int n = 0; n < 4; ++n)
#pragma unroll
      for (int r = 0; r < 4; ++r) {
        const int srow = s0 + w * 16 + lg * 4 + r;
        z[((size_t)b * S_ + srow) * DM + h * 64 + n * 16 + lr] = (__bf16)acc[n][r];
      }
  }
}

// ---------------------------------------------------------------------------
// K4: out = z @ Wb^T + bias.  M=16384, N=1024, K=1024.  BM=BN=128, BK=64.
// m97 structure: global_load_lds width-16 staging, XOR chunk-swizzle
// (pre-swizzled global SOURCE + swizzled LDS read -> conflict-free b128).
// Wb stored [n][k] bf16 = exactly the B^T layout. Output f32 + f32 bias.
// ---------------------------------------------------------------------------
__global__ __launch_bounds__(256)
void k4_out_gemm(const __bf16* __restrict__ zg,
                 const __bf16* __restrict__ Wb,
                 const float* __restrict__ biasg,
                 float* __restrict__ outg) {
  __shared__ __align__(16) __bf16 Alds[128 * 64];  // 16 KiB, swizzled
  __shared__ __align__(16) __bf16 Blds[128 * 64];
  const int bid = blockIdx.x;
  const int mblk = bid & 127, nblk = bid >> 7;
  const int m0 = mblk * 128, n0 = nblk * 128;
  const int t = threadIdx.x, wid = t >> 6, l = t & 63, lr = l & 15, lg = l >> 4;
  const int wr = wid >> 1, wc = wid & 1;
  f32x4 acc[4][4] = {};

  for (int kt = 0; kt < 16; ++kt) {
    const int k0 = kt * 64;
#pragma unroll
    for (int it = 0; it < 4; ++it) {
      const int idx = it * 256 + t;          // (row, 16B-chunk)
      const int row = idx >> 3, c = idx & 7;
      const int gc = c ^ (row & 7);          // pre-swizzled global source
      const void* gA = (const void*)(zg + ((size_t)(m0 + row)) * DM + k0 + gc * 8);
      const void* gB = (const void*)(Wb + ((size_t)(n0 + row)) * DM + k0 + gc * 8);
      void* lA = (void*)((char*)Alds + (it * 256 + wid * 64) * 16);  // wave-uniform
      void* lB = (void*)((char*)Blds + (it * 256 + wid * 64) * 16);
      gload_lds16(gA, lA);
      gload_lds16(gB, lB);
    }
    __syncthreads();
#pragma unroll
    for (int ks = 0; ks < 2; ++ks) {
      bf16x8 af[4], bfr[4];
#pragma unroll
      for (int mt = 0; mt < 4; ++mt) {
        const int row = wr * 64 + mt * 16 + lr;
        const int ch = (ks * 4 + lg) ^ (row & 7);
        af[mt] = *reinterpret_cast<const bf16x8*>((const char*)Alds + row * 128 + ch * 16);
      }
#pragma unroll
      for (int nt = 0; nt < 4; ++nt) {
        const int row = wc * 64 + nt * 16 + lr;
        const int ch = (ks * 4 + lg) ^ (row & 7);
        bfr[nt] = *reinterpret_cast<const bf16x8*>((const char*)Blds + row * 128 + ch * 16);
      }
#pragma unroll
      for (int mt = 0; mt < 4; ++mt)
#pragma unroll
        for (int nt = 0; nt < 4; ++nt)
          acc[mt][nt] = MFMA16(af[mt], bfr[nt], acc[mt][nt]);
    }
    __syncthreads();
  }

  // epilogue: + f32 bias, f32 store
#pragma unroll
  for (int nt = 0; nt < 4; ++nt) {
    const int colg = n0 + wc * 64 + nt * 16 + lr;
    const float bv = biasg[colg];
#pragma unroll
    for (int mt = 0; mt < 4; ++mt)
#pragma unroll
      for (int r = 0; r < 4; ++r) {
        const int rowg = m0 + wr * 64 + mt * 16 + lg * 4 + r;
        outg[(size_t)rowg * DM + colg] = acc[mt][nt][r] + bv;
      }
  }
}

extern "C" void kernel_launch(void* const* d_in, const int* in_sizes, int n_in,
                              void* d_out, int out_size, void* d_ws, size_t ws_size,
                              hipStream_t stream) {
  const float* Q = (const float*)d_in[0];
  const float* K = (const float*)d_in[1];
  const float* V = (const float*)d_in[2];
  const float* W = (const float*)d_in[3];
  const float* bias = (const float*)d_in[4];
  float* out = (float*)d_out;

  char* ws = (char*)d_ws;
  float* partial = (float*)ws;                                  // 16 MiB
  __bf16* kvt = (__bf16*)(ws + 16777216);                       // 512 KiB
  __bf16* Wb  = (__bf16*)(ws + 16777216 + 524288);              // 2 MiB
  __bf16* z   = (__bf16*)(ws + 16777216 + 524288 + 2097152);    // 32 MiB

  hipLaunchKernelGGL(k0_convw, dim3(1024), dim3(256), 0, stream, W, Wb);
  hipLaunchKernelGGL(k1_kv_partial, dim3(SPLIT * BH), dim3(256), 0, stream, K, V, partial);
  hipLaunchKernelGGL(k2_kv_reduce, dim3(BH), dim3(256), 0, stream, partial, kvt);
  hipLaunchKernelGGL(k3_z, dim3(B_ * (S_ / 64)), dim3(256), 0, stream, Q, kvt, z);
  hipLaunchKernelGGL(k4_out_gemm, dim3(1024), dim3(256), 0, stream, z, Wb, bias, out);
}